// Round 20
// baseline (1158.031 us; speedup 1.0000x reference)
//
#include <hip/hip_runtime.h>
#include <hip/hip_bf16.h>

// Problem constants
constexpr int H   = 8;
constexpr int B   = 32;
constexpr int SEQ = 4096;
constexpr int D   = 64;
constexpr int S   = 45;   // sample_k
constexpr int U   = 45;   // n_top
constexpr int HB  = H * B; // 256

typedef float f4v __attribute__((ext_vector_type(4)));
typedef int   i4v __attribute__((ext_vector_type(4)));

// LLVM raw buffer load intrinsic (CK pattern): compiler-tracked dependency,
// correct vmcnt insertion, SRSRC addressing with 32-bit voffset.
__device__ f4v llvm_raw_buffer_load_v4f32(i4v srsrc, int voffset, int soffset,
                                          int aux) __asm("llvm.amdgcn.raw.buffer.load.v4f32");

// ---------------------------------------------------------------------------
// async global->LDS, 16B per lane (used by k_attn staging).
// ---------------------------------------------------------------------------
__device__ __forceinline__ void stage16(const void* gsrc, void* ldst) {
    __builtin_amdgcn_global_load_lds(
        (const __attribute__((address_space(1))) unsigned int*)gsrc,
        (__attribute__((address_space(3))) unsigned int*)ldst,
        16, 0, 0);
}

// ---------------------------------------------------------------------------
// Kernel 1: sparsity measure. FROZEN at 610 us (T8 SRSRC ring, VGPR 56).
// 7 attempts (r8-r19) establish this as the structure's floor: 2x the 305us
// TA line floor, latency-limited at 43% occupancy.
// XCD remap (T1): hb === XCD (mod 8) keeps each hb's 1 MB K block L2-hot.
// ---------------------------------------------------------------------------
__global__ __launch_bounds__(256) void k_probe(const float* __restrict__ q,
                                               const float* __restrict__ k,
                                               const int* __restrict__ sidx,
                                               float* __restrict__ M) {
    __shared__ int sIdx[16][48];
    int xcd  = blockIdx.x & 7;
    int idx  = blockIdx.x >> 3;
    int qblk = idx & 255;
    int hb   = (idx >> 8) * 8 + xcd;
    int g    = threadIdx.x >> 4;
    int l    = threadIdx.x & 15;
    int i    = qblk * 16 + g;

    const int* ip = sidx + (size_t)i * S;
    sIdx[g][l]      = ip[l];
    sIdx[g][l + 16] = ip[l + 16];
    if (l + 32 < S) sIdx[g][l + 32] = ip[l + 32];
    __syncthreads();

    float4 qv = *(const float4*)(q + ((size_t)hb * SEQ + i) * D + l * 4);

    const float* kbase = k + (size_t)hb * SEQ * D;
    i4v rs;
    rs.x = (int)(unsigned int)(uintptr_t)kbase;
    rs.y = (int)(unsigned int)((uintptr_t)kbase >> 32);
    rs.z = SEQ * D * 4;
    rs.w = 0x00020000;
    int loff = l * 16;

    constexpr int PF = 5;
    f4v buf[PF];
#pragma unroll
    for (int p = 0; p < PF; ++p)
        buf[p] = llvm_raw_buffer_load_v4f32(rs, (sIdx[g][p] << 8) | loff, 0, 0);

    float mx = -1e30f, sm = 0.0f;
#pragma unroll
    for (int s = 0; s < S; ++s) {
        f4v kv = buf[s % PF];
        if (s + PF < S)
            buf[s % PF] = llvm_raw_buffer_load_v4f32(rs, (sIdx[g][s + PF] << 8) | loff, 0, 0);
        float p = qv.x * kv.x + qv.y * kv.y + qv.z * kv.z + qv.w * kv.w;
        p += __shfl_xor(p, 8, 64);
        p += __shfl_xor(p, 4, 64);
        p += __shfl_xor(p, 2, 64);
        p += __shfl_xor(p, 1, 64);
        mx = fmaxf(mx, p);
        sm += p;
    }
    if (l == 0) M[(size_t)hb * SEQ + i] = mx - sm * (1.0f / (float)SEQ);
}

// ---------------------------------------------------------------------------
// Kernel 2: top-45 indices of M per (h,b). Register-resident iterative
// argmax. Tie -> lowest index.
// ---------------------------------------------------------------------------
__global__ __launch_bounds__(256) void k_topk(const float* __restrict__ M,
                                              int* __restrict__ mtop) {
    __shared__ float rv[4];
    __shared__ int   ri[4];
    __shared__ int   win;
    int hb  = blockIdx.x;
    int tid = threadIdx.x;
    const float* Mr = M + (size_t)hb * SEQ;

    float vals[16];
#pragma unroll
    for (int r = 0; r < 16; ++r) vals[r] = Mr[tid + (r << 8)];

    for (int t = 0; t < U; ++t) {
        float bv = vals[0]; int br = 0;
#pragma unroll
        for (int r = 1; r < 16; ++r)
            if (vals[r] > bv) { bv = vals[r]; br = r; }
        int bi = tid + (br << 8);

#pragma unroll
        for (int off = 32; off; off >>= 1) {
            float ov = __shfl_down(bv, off, 64);
            int   oi = __shfl_down(bi, off, 64);
            if (ov > bv || (ov == bv && oi < bi)) { bv = ov; bi = oi; }
        }
        int w = tid >> 6;
        if ((tid & 63) == 0) { rv[w] = bv; ri[w] = bi; }
        __syncthreads();
        if (tid == 0) {
            for (int ww = 1; ww < 4; ++ww)
                if (rv[ww] > bv || (rv[ww] == bv && ri[ww] < bi)) { bv = rv[ww]; bi = ri[ww]; }
            mtop[hb * U + t] = bi;
            win = bi;
        }
        __syncthreads();
        int wi = win;
        if ((wi & 255) == tid) {
            int wr = wi >> 8;
#pragma unroll
            for (int r = 0; r < 16; ++r)
                if (r == wr) vals[r] = -1e30f;
        }
        __syncthreads();
    }
}

// ---------------------------------------------------------------------------
// Kernel 3: attention + fused v-mean + output fill for one (h,b).
// 512 threads = 8 waves; wave owns SIX queries (was 3 @ 16 waves) -> per-CU
// LDS read volume halves (32 MB -> 16 MB, the dominant attn floor). Wave w
// stages rows 8w..8w+7 of each tile via 2 calls per operand; counted
// vmcnt(8) two tiles ahead; TRIPLE-buffered LDS (96 KB). ~175 VGPR ->
// 2 waves/SIMD (dense independent FMA stream keeps VALU fed).
// ---------------------------------------------------------------------------
#define QK8(p, qsrow, k0, k1)                                             \
    p = qsrow[0]*k0.x + qsrow[1]*k0.y + qsrow[2]*k0.z + qsrow[3]*k0.w     \
      + qsrow[4]*k1.x + qsrow[5]*k1.y + qsrow[6]*k1.z + qsrow[7]*k1.w;

__global__ __launch_bounds__(512) void k_attn(const float* __restrict__ q,
                                              const float* __restrict__ k,
                                              const float* __restrict__ v,
                                              const int* __restrict__ mtop,
                                              float* __restrict__ out) {
    __shared__ float KB[3][64][64];
    __shared__ float VB[3][64][64];
    int hb   = blockIdx.x;
    int tid  = threadIdx.x;
    int w    = tid >> 6;      // wave 0..7
    int lane = tid & 63;
    int grp  = lane >> 3;     // key-group 0..7
    int l    = lane & 7;      // 8-float slice id

    // --- this wave's 6 queries ---
    int uq[6];
    float qs[6][8];
    const float* qb = q + (size_t)hb * SEQ * D;
#pragma unroll
    for (int qi = 0; qi < 6; ++qi) {
        int u = w * 6 + qi;
        uq[qi] = mtop[hb * U + (u < U ? u : U - 1)];
        const float* r = qb + (size_t)uq[qi] * D + l * 8;
        float4 a  = *(const float4*)r;
        float4 b4 = *(const float4*)(r + 4);
        qs[qi][0] = a.x * 0.125f;  qs[qi][1] = a.y * 0.125f;
        qs[qi][2] = a.z * 0.125f;  qs[qi][3] = a.w * 0.125f;
        qs[qi][4] = b4.x * 0.125f; qs[qi][5] = b4.y * 0.125f;
        qs[qi][6] = b4.z * 0.125f; qs[qi][7] = b4.w * 0.125f;
    }

    // --- staging addresses: wave w stages rows 8w..8w+7 (2 calls/operand) ---
    const char* kg = (const char*)(k + (size_t)hb * SEQ * D);
    const char* vg = (const char*)(v + (size_t)hb * SEQ * D);
    int r0 = 8 * w + (lane >> 4);        // call 0: rows 8w..8w+3
    int r1 = r0 + 4;                     // call 1: rows 8w+4..8w+7
    size_t sgo0 = (size_t)r0 * 256 + (size_t)(((lane & 15) * 16) ^ ((r0 & 7) << 4));
    size_t sgo1 = (size_t)r1 * 256 + (size_t)(((lane & 15) * 16) ^ ((r1 & 7) << 4));

#define STAGE_TILE(tt, bn)                                                           \
    stage16(kg + (size_t)(tt) * 16384 + sgo0, (char*)KB + (bn) * 16384 + w * 2048);          \
    stage16(kg + (size_t)(tt) * 16384 + sgo1, (char*)KB + (bn) * 16384 + w * 2048 + 1024);   \
    stage16(vg + (size_t)(tt) * 16384 + sgo0, (char*)VB + (bn) * 16384 + w * 2048);          \
    stage16(vg + (size_t)(tt) * 16384 + sgo1, (char*)VB + (bn) * 16384 + w * 2048 + 1024);

    float m[6], ls[6], O[6][8], vsum[8];
#pragma unroll
    for (int qi = 0; qi < 6; ++qi) {
        m[qi] = -1e30f; ls[qi] = 0.0f;
#pragma unroll
        for (int d = 0; d < 8; ++d) O[qi][d] = 0.0f;
    }
#pragma unroll
    for (int d = 0; d < 8; ++d) vsum[d] = 0.0f;

    int rb = (l * 32) ^ (grp << 4);   // swizzled col byte

    // --- prologue: stage tiles 0 and 1 ---
    STAGE_TILE(0, 0)
    STAGE_TILE(1, 1)

    for (int t = 0; t < 64; ++t) {
        if (t < 62) { STAGE_TILE(t + 2, (t + 2) % 3) }
        if (t < 62)      { asm volatile("s_waitcnt vmcnt(8)" ::: "memory"); }
        else if (t == 62){ asm volatile("s_waitcnt vmcnt(4)" ::: "memory"); }
        else             { asm volatile("s_waitcnt vmcnt(0)" ::: "memory"); }
        __builtin_amdgcn_s_barrier();
        __builtin_amdgcn_sched_barrier(0);

        const char* KBc = (const char*)KB + (t % 3) * 16384;
        const char* VBc = (const char*)VB + (t % 3) * 16384;

        float s[6][8];
#pragma unroll
        for (int sub = 0; sub < 8; ++sub) {
            int j = sub * 8 + grp;
            const float4 ka  = *(const float4*)(KBc + j * 256 + rb);
            const float4 kb2 = *(const float4*)(KBc + j * 256 + (rb ^ 16));
#pragma unroll
            for (int qi = 0; qi < 6; ++qi) {
                float p;
                QK8(p, qs[qi], ka, kb2);
                p += __shfl_xor(p, 1, 64);
                p += __shfl_xor(p, 2, 64);
                p += __shfl_xor(p, 4, 64);
                s[qi][sub] = p;
            }
        }
        // tile max per query, rescale
#pragma unroll
        for (int qi = 0; qi < 6; ++qi) {
            float tm = s[qi][0];
#pragma unroll
            for (int e = 1; e < 8; ++e) tm = fmaxf(tm, s[qi][e]);
            tm = fmaxf(tm, __shfl_xor(tm, 8, 64));
            tm = fmaxf(tm, __shfl_xor(tm, 16, 64));
            tm = fmaxf(tm, __shfl_xor(tm, 32, 64));
            float nm = fmaxf(m[qi], tm);
            float c  = __expf(m[qi] - nm);
            m[qi] = nm;
            ls[qi] *= c;
#pragma unroll
            for (int d = 0; d < 8; ++d) O[qi][d] *= c;
        }
        // PV + v-mean
#pragma unroll
        for (int sub = 0; sub < 8; ++sub) {
            int j = sub * 8 + grp;
            const float4 va  = *(const float4*)(VBc + j * 256 + rb);
            const float4 vb2 = *(const float4*)(VBc + j * 256 + (rb ^ 16));
            vsum[0] += va.x;  vsum[1] += va.y;  vsum[2] += va.z;  vsum[3] += va.w;
            vsum[4] += vb2.x; vsum[5] += vb2.y; vsum[6] += vb2.z; vsum[7] += vb2.w;
#pragma unroll
            for (int qi = 0; qi < 6; ++qi) {
                float pp = __expf(s[qi][sub] - m[qi]);
                ls[qi] += pp;
                O[qi][0] = fmaf(pp, va.x,  O[qi][0]);
                O[qi][1] = fmaf(pp, va.y,  O[qi][1]);
                O[qi][2] = fmaf(pp, va.z,  O[qi][2]);
                O[qi][3] = fmaf(pp, va.w,  O[qi][3]);
                O[qi][4] = fmaf(pp, vb2.x, O[qi][4]);
                O[qi][5] = fmaf(pp, vb2.y, O[qi][5]);
                O[qi][6] = fmaf(pp, vb2.z, O[qi][6]);
                O[qi][7] = fmaf(pp, vb2.w, O[qi][7]);
            }
        }
        asm volatile("" ::: "memory");
        __builtin_amdgcn_s_barrier();   // reads done before buffer reuse
        __builtin_amdgcn_sched_barrier(0);
    }

    // --- reduce O / ls / vsum across the 8 key-groups ---
#pragma unroll
    for (int qi = 0; qi < 6; ++qi) {
#pragma unroll
        for (int d = 0; d < 8; ++d) {
            O[qi][d] += __shfl_xor(O[qi][d], 8, 64);
            O[qi][d] += __shfl_xor(O[qi][d], 16, 64);
            O[qi][d] += __shfl_xor(O[qi][d], 32, 64);
        }
        ls[qi] += __shfl_xor(ls[qi], 8, 64);
        ls[qi] += __shfl_xor(ls[qi], 16, 64);
        ls[qi] += __shfl_xor(ls[qi], 32, 64);
    }
#pragma unroll
    for (int d = 0; d < 8; ++d) {
        vsum[d] += __shfl_xor(vsum[d], 8, 64);
        vsum[d] += __shfl_xor(vsum[d], 16, 64);
        vsum[d] += __shfl_xor(vsum[d], 32, 64);
    }

    float* ob = out + (size_t)hb * SEQ * D;

    // --- fill this hb's whole output with vmean (wave w -> rows 512w..) ---
    float4 vm0, vm1;
    {
        float inv = 1.0f / (float)SEQ;
        vm0 = make_float4(vsum[0]*inv, vsum[1]*inv, vsum[2]*inv, vsum[3]*inv);
        vm1 = make_float4(vsum[4]*inv, vsum[5]*inv, vsum[6]*inv, vsum[7]*inv);
    }
    {
        int rbase = w * 512 + grp;
        for (int rr = 0; rr < 512; rr += 8) {
            float* p = ob + (size_t)(rbase + rr) * D + l * 8;
            *(float4*)(p)     = vm0;
            *(float4*)(p + 4) = vm1;
        }
    }
    __syncthreads();   // fill ordered before overwrite

    // --- scatter the attended rows (group qi writes query qi; exclusive) ---
#pragma unroll
    for (int qi = 0; qi < 6; ++qi) {
        if (grp == qi && (w * 6 + qi) < U) {
            float inv = 1.0f / ls[qi];
            float* p = ob + (size_t)uq[qi] * D + l * 8;
            *(float4*)(p)     = make_float4(O[qi][0]*inv, O[qi][1]*inv, O[qi][2]*inv, O[qi][3]*inv);
            *(float4*)(p + 4) = make_float4(O[qi][4]*inv, O[qi][5]*inv, O[qi][6]*inv, O[qi][7]*inv);
        }
    }
}

// ---------------------------------------------------------------------------
extern "C" void kernel_launch(void* const* d_in, const int* in_sizes, int n_in,
                              void* d_out, int out_size, void* d_ws, size_t ws_size,
                              hipStream_t stream) {
    const float* q    = (const float*)d_in[0];
    const float* k    = (const float*)d_in[1];
    const float* v    = (const float*)d_in[2];
    const int*   sidx = (const int*)d_in[3];
    float* out = (float*)d_out;

    char* ws = (char*)d_ws;
    float* M    = (float*)ws;                         // 4 MB
    int*   mtop = (int*)(ws + (size_t)HB * SEQ * 4);  // 46 KB

    k_probe<<<HB * (SEQ / 16), 256, 0, stream>>>(q, k, sidx, M);
    k_topk <<<HB, 256,  0, stream>>>(M, mtop);
    k_attn <<<HB, 512, 0, stream>>>(q, k, v, mtop, out);
}

// Round 21
// 1098.159 us; speedup vs baseline: 1.0545x; 1.0545x over previous
//
#include <hip/hip_runtime.h>
#include <hip/hip_bf16.h>

// Problem constants
constexpr int H   = 8;
constexpr int B   = 32;
constexpr int SEQ = 4096;
constexpr int D   = 64;
constexpr int S   = 45;   // sample_k
constexpr int U   = 45;   // n_top
constexpr int HB  = H * B; // 256

typedef float f4v __attribute__((ext_vector_type(4)));
typedef int   i4v __attribute__((ext_vector_type(4)));

// LLVM raw buffer load intrinsic (CK pattern): compiler-tracked dependency,
// correct vmcnt insertion, SRSRC addressing with 32-bit voffset.
__device__ f4v llvm_raw_buffer_load_v4f32(i4v srsrc, int voffset, int soffset,
                                          int aux) __asm("llvm.amdgcn.raw.buffer.load.v4f32");

// ---------------------------------------------------------------------------
// async global->LDS, 16B per lane (used by k_attn staging).
// ---------------------------------------------------------------------------
__device__ __forceinline__ void stage16(const void* gsrc, void* ldst) {
    __builtin_amdgcn_global_load_lds(
        (const __attribute__((address_space(1))) unsigned int*)gsrc,
        (__attribute__((address_space(3))) unsigned int*)ldst,
        16, 0, 0);
}

// ---------------------------------------------------------------------------
// Kernel 1: sparsity measure. BEST-KNOWN (r18): T8 SRSRC ring, VGPR 56,
// 610 us. r20 retro: this is the structure's floor (7 attempts, r8-r19).
// XCD remap (T1): hb === XCD (mod 8) keeps each hb's 1 MB K block L2-hot.
// ---------------------------------------------------------------------------
__global__ __launch_bounds__(256) void k_probe(const float* __restrict__ q,
                                               const float* __restrict__ k,
                                               const int* __restrict__ sidx,
                                               float* __restrict__ M) {
    __shared__ int sIdx[16][48];
    int xcd  = blockIdx.x & 7;
    int idx  = blockIdx.x >> 3;
    int qblk = idx & 255;
    int hb   = (idx >> 8) * 8 + xcd;
    int g    = threadIdx.x >> 4;
    int l    = threadIdx.x & 15;
    int i    = qblk * 16 + g;

    const int* ip = sidx + (size_t)i * S;
    sIdx[g][l]      = ip[l];
    sIdx[g][l + 16] = ip[l + 16];
    if (l + 32 < S) sIdx[g][l + 32] = ip[l + 32];
    __syncthreads();

    float4 qv = *(const float4*)(q + ((size_t)hb * SEQ + i) * D + l * 4);

    // buffer descriptor for this hb's K block (1 MB, stride 0, raw dwords)
    const float* kbase = k + (size_t)hb * SEQ * D;
    i4v rs;
    rs.x = (int)(unsigned int)(uintptr_t)kbase;
    rs.y = (int)(unsigned int)((uintptr_t)kbase >> 32);
    rs.z = SEQ * D * 4;          // num_records (bytes)
    rs.w = 0x00020000;           // raw untyped dword access
    int loff = l * 16;           // byte offset within a 256 B row

    constexpr int PF = 4;
    f4v buf[PF];
#pragma unroll
    for (int p = 0; p < PF; ++p)
        buf[p] = llvm_raw_buffer_load_v4f32(rs, (sIdx[g][p] << 8) | loff, 0, 0);

    float mx = -1e30f, sm = 0.0f;
#pragma unroll
    for (int s = 0; s < S; ++s) {
        f4v kv = buf[s % PF];
        if (s + PF < S)          // compile-time under full unroll
            buf[s % PF] = llvm_raw_buffer_load_v4f32(rs, (sIdx[g][s + PF] << 8) | loff, 0, 0);
        float p = qv.x * kv.x + qv.y * kv.y + qv.z * kv.z + qv.w * kv.w;
        p += __shfl_xor(p, 8, 64);
        p += __shfl_xor(p, 4, 64);
        p += __shfl_xor(p, 2, 64);
        p += __shfl_xor(p, 1, 64);
        mx = fmaxf(mx, p);
        sm += p;
    }
    if (l == 0) M[(size_t)hb * SEQ + i] = mx - sm * (1.0f / (float)SEQ);
}

// ---------------------------------------------------------------------------
// Kernel 2: top-45 indices of M per (h,b). Register-resident iterative
// argmax. Tie -> lowest index.
// ---------------------------------------------------------------------------
__global__ __launch_bounds__(256) void k_topk(const float* __restrict__ M,
                                              int* __restrict__ mtop) {
    __shared__ float rv[4];
    __shared__ int   ri[4];
    __shared__ int   win;
    int hb  = blockIdx.x;
    int tid = threadIdx.x;
    const float* Mr = M + (size_t)hb * SEQ;

    float vals[16];
#pragma unroll
    for (int r = 0; r < 16; ++r) vals[r] = Mr[tid + (r << 8)];

    for (int t = 0; t < U; ++t) {
        float bv = vals[0]; int br = 0;
#pragma unroll
        for (int r = 1; r < 16; ++r)
            if (vals[r] > bv) { bv = vals[r]; br = r; }
        int bi = tid + (br << 8);

#pragma unroll
        for (int off = 32; off; off >>= 1) {
            float ov = __shfl_down(bv, off, 64);
            int   oi = __shfl_down(bi, off, 64);
            if (ov > bv || (ov == bv && oi < bi)) { bv = ov; bi = oi; }
        }
        int w = tid >> 6;
        if ((tid & 63) == 0) { rv[w] = bv; ri[w] = bi; }
        __syncthreads();
        if (tid == 0) {
            for (int ww = 1; ww < 4; ++ww)
                if (rv[ww] > bv || (rv[ww] == bv && ri[ww] < bi)) { bv = rv[ww]; bi = ri[ww]; }
            mtop[hb * U + t] = bi;
            win = bi;
        }
        __syncthreads();
        int wi = win;
        if ((wi & 255) == tid) {
            int wr = wi >> 8;
#pragma unroll
            for (int r = 0; r < 16; ++r)
                if (r == wr) vals[r] = -1e30f;
        }
        __syncthreads();
    }
}

// ---------------------------------------------------------------------------
// Kernel 3: attention + fused v-mean + output fill for one (h,b).
// BEST-KNOWN (r14/r18): 1024 threads = 16 waves; wave owns 3 queries, walks
// all 4096 keys. TRIPLE-buffered LDS (96 KB) with counted vmcnt + raw
// s_barrier (T4). v-mean from staged V; epilogue fills the 1 MB output
// block then overwrites the 45 attn rows. r15 (4-block split), r20 (6q/8w)
// both regressed: the 16-wave/4-per-SIMD balance is this kernel's optimum.
// ---------------------------------------------------------------------------
#define QK8(p, qsrow, k0, k1)                                             \
    p = qsrow[0]*k0.x + qsrow[1]*k0.y + qsrow[2]*k0.z + qsrow[3]*k0.w     \
      + qsrow[4]*k1.x + qsrow[5]*k1.y + qsrow[6]*k1.z + qsrow[7]*k1.w;

__global__ __launch_bounds__(1024, 4) void k_attn(const float* __restrict__ q,
                                                  const float* __restrict__ k,
                                                  const float* __restrict__ v,
                                                  const int* __restrict__ mtop,
                                                  float* __restrict__ out) {
    __shared__ float KB[3][64][64];
    __shared__ float VB[3][64][64];
    int hb   = blockIdx.x;
    int tid  = threadIdx.x;
    int w    = tid >> 6;      // wave 0..15
    int lane = tid & 63;
    int grp  = lane >> 3;     // key-group 0..7
    int l    = lane & 7;      // 8-float slice id

    int u0 = w * 3, u1 = w * 3 + 1, u2 = w * 3 + 2;
    int uq0 = mtop[hb * U + (u0 < U ? u0 : U - 1)];
    int uq1 = mtop[hb * U + (u1 < U ? u1 : U - 1)];
    int uq2 = mtop[hb * U + (u2 < U ? u2 : U - 1)];
    const float* qb = q + (size_t)hb * SEQ * D;
    float qs0[8], qs1[8], qs2[8];
    {
        const float* r0 = qb + (size_t)uq0 * D + l * 8;
        const float* r1 = qb + (size_t)uq1 * D + l * 8;
        const float* r2 = qb + (size_t)uq2 * D + l * 8;
        float4 a, b4;
        a = *(const float4*)r0; b4 = *(const float4*)(r0 + 4);
        qs0[0]=a.x*0.125f; qs0[1]=a.y*0.125f; qs0[2]=a.z*0.125f; qs0[3]=a.w*0.125f;
        qs0[4]=b4.x*0.125f; qs0[5]=b4.y*0.125f; qs0[6]=b4.z*0.125f; qs0[7]=b4.w*0.125f;
        a = *(const float4*)r1; b4 = *(const float4*)(r1 + 4);
        qs1[0]=a.x*0.125f; qs1[1]=a.y*0.125f; qs1[2]=a.z*0.125f; qs1[3]=a.w*0.125f;
        qs1[4]=b4.x*0.125f; qs1[5]=b4.y*0.125f; qs1[6]=b4.z*0.125f; qs1[7]=b4.w*0.125f;
        a = *(const float4*)r2; b4 = *(const float4*)(r2 + 4);
        qs2[0]=a.x*0.125f; qs2[1]=a.y*0.125f; qs2[2]=a.z*0.125f; qs2[3]=a.w*0.125f;
        qs2[4]=b4.x*0.125f; qs2[5]=b4.y*0.125f; qs2[6]=b4.z*0.125f; qs2[7]=b4.w*0.125f;
    }

    const char* kg = (const char*)(k + (size_t)hb * SEQ * D);
    const char* vg = (const char*)(v + (size_t)hb * SEQ * D);
    int srow = 4 * w + (lane >> 4);
    size_t sgo = (size_t)srow * 256 + (size_t)(((lane & 15) * 16) ^ ((srow & 7) << 4));

    float m0 = -1e30f, m1 = -1e30f, m2 = -1e30f;
    float ls0 = 0.0f, ls1 = 0.0f, ls2 = 0.0f;
    float O0[8], O1[8], O2[8], vsum[8];
#pragma unroll
    for (int d = 0; d < 8; ++d) { O0[d]=0.0f; O1[d]=0.0f; O2[d]=0.0f; vsum[d]=0.0f; }

    int rb = (l * 32) ^ (grp << 4);

    stage16(kg + sgo,         (char*)KB + 0 * 16384 + w * 1024);
    stage16(vg + sgo,         (char*)VB + 0 * 16384 + w * 1024);
    stage16(kg + 16384 + sgo, (char*)KB + 1 * 16384 + w * 1024);
    stage16(vg + 16384 + sgo, (char*)VB + 1 * 16384 + w * 1024);

    for (int t = 0; t < 64; ++t) {
        if (t < 62) {
            int bn = (t + 2) % 3;
            stage16(kg + (size_t)(t + 2) * 16384 + sgo, (char*)KB + bn * 16384 + w * 1024);
            stage16(vg + (size_t)(t + 2) * 16384 + sgo, (char*)VB + bn * 16384 + w * 1024);
        }
        if (t < 62)      { asm volatile("s_waitcnt vmcnt(4)" ::: "memory"); }
        else if (t == 62){ asm volatile("s_waitcnt vmcnt(2)" ::: "memory"); }
        else             { asm volatile("s_waitcnt vmcnt(0)" ::: "memory"); }
        __builtin_amdgcn_s_barrier();
        __builtin_amdgcn_sched_barrier(0);

        const char* KBc = (const char*)KB + (t % 3) * 16384;
        const char* VBc = (const char*)VB + (t % 3) * 16384;

        float s0[8], s1[8], s2[8];
#pragma unroll
        for (int sub = 0; sub < 8; ++sub) {
            int j = sub * 8 + grp;
            const float4 ka = *(const float4*)(KBc + j * 256 + rb);
            const float4 kb2 = *(const float4*)(KBc + j * 256 + (rb ^ 16));
            float p0, p1, p2;
            QK8(p0, qs0, ka, kb2);
            QK8(p1, qs1, ka, kb2);
            QK8(p2, qs2, ka, kb2);
            p0 += __shfl_xor(p0, 1, 64); p0 += __shfl_xor(p0, 2, 64); p0 += __shfl_xor(p0, 4, 64);
            p1 += __shfl_xor(p1, 1, 64); p1 += __shfl_xor(p1, 2, 64); p1 += __shfl_xor(p1, 4, 64);
            p2 += __shfl_xor(p2, 1, 64); p2 += __shfl_xor(p2, 2, 64); p2 += __shfl_xor(p2, 4, 64);
            s0[sub] = p0; s1[sub] = p1; s2[sub] = p2;
        }
        float t0 = s0[0], t1 = s1[0], t2 = s2[0];
#pragma unroll
        for (int e = 1; e < 8; ++e) {
            t0 = fmaxf(t0, s0[e]); t1 = fmaxf(t1, s1[e]); t2 = fmaxf(t2, s2[e]);
        }
        t0 = fmaxf(t0, __shfl_xor(t0, 8, 64));  t0 = fmaxf(t0, __shfl_xor(t0, 16, 64)); t0 = fmaxf(t0, __shfl_xor(t0, 32, 64));
        t1 = fmaxf(t1, __shfl_xor(t1, 8, 64));  t1 = fmaxf(t1, __shfl_xor(t1, 16, 64)); t1 = fmaxf(t1, __shfl_xor(t1, 32, 64));
        t2 = fmaxf(t2, __shfl_xor(t2, 8, 64));  t2 = fmaxf(t2, __shfl_xor(t2, 16, 64)); t2 = fmaxf(t2, __shfl_xor(t2, 32, 64));
        float n0 = fmaxf(m0, t0), n1 = fmaxf(m1, t1), n2 = fmaxf(m2, t2);
        float c0 = __expf(m0 - n0), c1 = __expf(m1 - n1), c2 = __expf(m2 - n2);
        m0 = n0; m1 = n1; m2 = n2;
        ls0 *= c0; ls1 *= c1; ls2 *= c2;
#pragma unroll
        for (int d = 0; d < 8; ++d) { O0[d] *= c0; O1[d] *= c1; O2[d] *= c2; }

#pragma unroll
        for (int sub = 0; sub < 8; ++sub) {
            int j = sub * 8 + grp;
            const float4 va = *(const float4*)(VBc + j * 256 + rb);
            const float4 vb2 = *(const float4*)(VBc + j * 256 + (rb ^ 16));
            vsum[0] += va.x;  vsum[1] += va.y;  vsum[2] += va.z;  vsum[3] += va.w;
            vsum[4] += vb2.x; vsum[5] += vb2.y; vsum[6] += vb2.z; vsum[7] += vb2.w;
            float p0 = __expf(s0[sub] - m0);
            float p1 = __expf(s1[sub] - m1);
            float p2 = __expf(s2[sub] - m2);
            ls0 += p0; ls1 += p1; ls2 += p2;
            O0[0] = fmaf(p0, va.x, O0[0]); O0[1] = fmaf(p0, va.y, O0[1]);
            O0[2] = fmaf(p0, va.z, O0[2]); O0[3] = fmaf(p0, va.w, O0[3]);
            O0[4] = fmaf(p0, vb2.x, O0[4]); O0[5] = fmaf(p0, vb2.y, O0[5]);
            O0[6] = fmaf(p0, vb2.z, O0[6]); O0[7] = fmaf(p0, vb2.w, O0[7]);
            O1[0] = fmaf(p1, va.x, O1[0]); O1[1] = fmaf(p1, va.y, O1[1]);
            O1[2] = fmaf(p1, va.z, O1[2]); O1[3] = fmaf(p1, va.w, O1[3]);
            O1[4] = fmaf(p1, vb2.x, O1[4]); O1[5] = fmaf(p1, vb2.y, O1[5]);
            O1[6] = fmaf(p1, vb2.z, O1[6]); O1[7] = fmaf(p1, vb2.w, O1[7]);
            O2[0] = fmaf(p2, va.x, O2[0]); O2[1] = fmaf(p2, va.y, O2[1]);
            O2[2] = fmaf(p2, va.z, O2[2]); O2[3] = fmaf(p2, va.w, O2[3]);
            O2[4] = fmaf(p2, vb2.x, O2[4]); O2[5] = fmaf(p2, vb2.y, O2[5]);
            O2[6] = fmaf(p2, vb2.z, O2[6]); O2[7] = fmaf(p2, vb2.w, O2[7]);
        }
        asm volatile("" ::: "memory");
        __builtin_amdgcn_s_barrier();
        __builtin_amdgcn_sched_barrier(0);
    }

#pragma unroll
    for (int d = 0; d < 8; ++d) {
        O0[d] += __shfl_xor(O0[d], 8, 64);  O0[d] += __shfl_xor(O0[d], 16, 64); O0[d] += __shfl_xor(O0[d], 32, 64);
        O1[d] += __shfl_xor(O1[d], 8, 64);  O1[d] += __shfl_xor(O1[d], 16, 64); O1[d] += __shfl_xor(O1[d], 32, 64);
        O2[d] += __shfl_xor(O2[d], 8, 64);  O2[d] += __shfl_xor(O2[d], 16, 64); O2[d] += __shfl_xor(O2[d], 32, 64);
        vsum[d] += __shfl_xor(vsum[d], 8, 64); vsum[d] += __shfl_xor(vsum[d], 16, 64); vsum[d] += __shfl_xor(vsum[d], 32, 64);
    }
    ls0 += __shfl_xor(ls0, 8, 64); ls0 += __shfl_xor(ls0, 16, 64); ls0 += __shfl_xor(ls0, 32, 64);
    ls1 += __shfl_xor(ls1, 8, 64); ls1 += __shfl_xor(ls1, 16, 64); ls1 += __shfl_xor(ls1, 32, 64);
    ls2 += __shfl_xor(ls2, 8, 64); ls2 += __shfl_xor(ls2, 16, 64); ls2 += __shfl_xor(ls2, 32, 64);

    float* ob = out + (size_t)hb * SEQ * D;

    float4 vm0, vm1;
    {
        float inv = 1.0f / (float)SEQ;
        vm0 = make_float4(vsum[0]*inv, vsum[1]*inv, vsum[2]*inv, vsum[3]*inv);
        vm1 = make_float4(vsum[4]*inv, vsum[5]*inv, vsum[6]*inv, vsum[7]*inv);
    }
    {
        int rbase = w * 256 + grp;
        for (int rr = 0; rr < 256; rr += 8) {
            float* p = ob + (size_t)(rbase + rr) * D + l * 8;
            *(float4*)(p)     = vm0;
            *(float4*)(p + 4) = vm1;
        }
    }
    __syncthreads();

    if (grp == 0 && u0 < U) {
        float inv = 1.0f / ls0;
        float* p = ob + (size_t)uq0 * D + l * 8;
        *(float4*)(p)     = make_float4(O0[0]*inv, O0[1]*inv, O0[2]*inv, O0[3]*inv);
        *(float4*)(p + 4) = make_float4(O0[4]*inv, O0[5]*inv, O0[6]*inv, O0[7]*inv);
    }
    if (grp == 1 && u1 < U) {
        float inv = 1.0f / ls1;
        float* p = ob + (size_t)uq1 * D + l * 8;
        *(float4*)(p)     = make_float4(O1[0]*inv, O1[1]*inv, O1[2]*inv, O1[3]*inv);
        *(float4*)(p + 4) = make_float4(O1[4]*inv, O1[5]*inv, O1[6]*inv, O1[7]*inv);
    }
    if (grp == 2 && u2 < U) {
        float inv = 1.0f / ls2;
        float* p = ob + (size_t)uq2 * D + l * 8;
        *(float4*)(p)     = make_float4(O2[0]*inv, O2[1]*inv, O2[2]*inv, O2[3]*inv);
        *(float4*)(p + 4) = make_float4(O2[4]*inv, O2[5]*inv, O2[6]*inv, O2[7]*inv);
    }
}

// ---------------------------------------------------------------------------
extern "C" void kernel_launch(void* const* d_in, const int* in_sizes, int n_in,
                              void* d_out, int out_size, void* d_ws, size_t ws_size,
                              hipStream_t stream) {
    const float* q    = (const float*)d_in[0];
    const float* k    = (const float*)d_in[1];
    const float* v    = (const float*)d_in[2];
    const int*   sidx = (const int*)d_in[3];
    float* out = (float*)d_out;

    char* ws = (char*)d_ws;
    float* M    = (float*)ws;                         // 4 MB
    int*   mtop = (int*)(ws + (size_t)HB * SEQ * 4);  // 46 KB

    k_probe<<<HB * (SEQ / 16), 256, 0, stream>>>(q, k, sidx, M);
    k_topk <<<HB, 256,  0, stream>>>(M, mtop);
    k_attn <<<HB, 1024, 0, stream>>>(q, k, v, mtop, out);
}